// Round 17
// baseline (29.022 us; speedup 1.0000x reference)
//
#include <hip/hip_runtime.h>

#define BSZ 4
#define CH  64
#define CE  8      // C/8
#define HW  4096
#define PJ  1088   // per-block partials: A 512 + B 512 + S 64

// ---------------------------------------------------------------------------
// K1: R15 structure (512 thr = 8 waves, 10 ch/wave) + xv register-pin.
// The asm "+v" pin after each x load forbids rematerialization: R13-R15
// builds show VGPR 40-52 => compiler re-loads x inside the o-loop
// (~640 VMEM instr/thread, issue-bound ~2.1us). Pinning forces 64 live
// VGPRs -> 64 VMEM loads total. No pointer arrays (R14 spill lesson).
// ---------------------------------------------------------------------------
__global__ __launch_bounds__(512) void k1_kernel(
    const float* __restrict__ x,
    const float* __restrict__ qlw, const float* __restrict__ qlb,
    const float* __restrict__ kw,  const float* __restrict__ kb,
    const float* __restrict__ vw,  const float* __restrict__ vb,
    const float* __restrict__ qgw, const float* __restrict__ qgb,
    float* __restrict__ kbuf, float* __restrict__ qlbuf, float* __restrict__ Pbuf)
{
    __shared__ float vT[CH][68];     // [channel][pp]
    __shared__ float kT[CE][64];     // [e][pp]

    const int tid  = threadIdx.x;
    const int lane = tid & 63;
    const int g    = __builtin_amdgcn_readfirstlane(tid >> 6);  // wave 0..7
    const int b    = blockIdx.x >> 6;
    const int p0   = (blockIdx.x & 63) << 6;
    const int p    = p0 | lane;

    float xv[CH];
#pragma unroll
    for (int c = 0; c < CH; ++c) {
        xv[c] = x[(((b << 6) + c) << 12) + p];
        asm volatile("" : "+v"(xv[c]));   // pin: forbid remat/re-load
    }

    const int o0 = g * 10;           // scalar
#pragma unroll
    for (int i = 0; i < 10; ++i) {
        const int o = o0 + i;        // scalar 0..79
        const float* wr;
        float bias;
        if (o < 8)       { wr = kw  + (o << 6);        bias = kb[o]; }
        else if (o < 16) { wr = qlw + ((o - 8) << 6);  bias = qlb[o - 8]; }
        else             { wr = vw  + ((o - 16) << 6); bias = vb[o - 16]; }
        float acc = bias;
#pragma unroll
        for (int c = 0; c < CH; ++c) acc += wr[c] * xv[c];   // v_fmac v,s,v
        if (o < 8) {
            kbuf[(((b << 3) + o) << 12) + p] = acc;
            kT[o][lane] = acc;
        } else if (o < 16) {
            qlbuf[(((b << 3) + (o - 8)) << 12) + p] = acc;
        } else {
            vT[o - 16][lane] = acc;
        }
    }
    __syncthreads();

    {
        const int e = g & 7;         // scalar
        float a = 0.f, bb = 0.f;
#pragma unroll
        for (int pp = 0; pp < 64; pp += 4) {
            const float4 vv = *reinterpret_cast<const float4*>(&vT[lane][pp]);
            const float4 kk = *reinterpret_cast<const float4*>(&kT[e][pp]);
            const float w0 = qgw[((p0 + pp + 0) << 3) + e];   // s_load
            const float w1 = qgw[((p0 + pp + 1) << 3) + e];
            const float w2 = qgw[((p0 + pp + 2) << 3) + e];
            const float w3 = qgw[((p0 + pp + 3) << 3) + e];
            a  += vv.x * w0 + vv.y * w1 + vv.z * w2 + vv.w * w3;
            bb += vv.x * kk.x + vv.y * kk.y + vv.z * kk.z + vv.w * kk.w;
        }
        float* P = Pbuf + (size_t)blockIdx.x * PJ;
        P[(e << 6) + lane] = a;              // coalesced per wave
        P[512 + (e << 6) + lane] = bb;
        if (g == 0) {
            float s = 0.f;
#pragma unroll
            for (int pp = 0; pp < 64; pp += 4) {
                const float4 vv = *reinterpret_cast<const float4*>(&vT[lane][pp]);
                s += vv.x * qgb[p0 + pp] + vv.y * qgb[p0 + pp + 1]
                   + vv.z * qgb[p0 + pp + 2] + vv.w * qgb[p0 + pp + 3];
            }
            P[1024 + lane] = s;
        }
    }
}

// ---------------------------------------------------------------------------
// KR: VERBATIM R15. 68 blocks x 256 threads; block owns 64 consecutive j;
// wave-loads are 64 consecutive floats (full lines); LDS [4][64] combine;
// gg/gl folded HERE (and only here).
// ---------------------------------------------------------------------------
__global__ __launch_bounds__(256) void kr_kernel(
    const float* __restrict__ Pbuf,
    const float* __restrict__ ggp, const float* __restrict__ glp,
    float* __restrict__ Fbuf)
{
    __shared__ float red[4][64];

    const int t    = threadIdx.x;
    const int jl   = t & 63;
    const int grp  = t >> 6;                         // 0..3
    const int j0   = blockIdx.x << 6;                // 0,64,...,4288
    const int b    = __builtin_amdgcn_readfirstlane(j0 / PJ);
    const int jj   = (j0 - b * PJ) + jl;             // 0..1087

    const float* Pb = Pbuf + ((size_t)(b << 6) + (grp << 4)) * PJ + jj;
    float acc = 0.f;
#pragma unroll
    for (int s = 0; s < 16; ++s) acc += Pb[(size_t)s * PJ];  // coalesced

    red[grp][jl] = acc;
    __syncthreads();

    if (t < 64) {
        const float sum = red[0][t] + red[1][t] + red[2][t] + red[3][t];
        const int jjo = (j0 - b * PJ) + t;
        const float scale = (jjo >= 512 && jjo < 1024) ? glp[0] : ggp[0];
        Fbuf[j0 + t] = scale * sum;                  // coalesced
    }
}

// ---------------------------------------------------------------------------
// K2: VERBATIM R15 (512 threads). F staged through LDS via coalesced VMEM
// (raw; gg/gl folded by kr); kg/ql/x register-prefetched before the barrier.
//   out[b,c,p] = dot8(kg[p],ggA[c]) + ggS[c] + dot8(ql[p],glB[c]) + x[b,c,p]
// kg[b,p,e] = kbuf flat at b*32768 + p*8 + e (raw reshape regroup).
// ---------------------------------------------------------------------------
__global__ __launch_bounds__(512) void k2_kernel(
    const float* __restrict__ x,
    const float* __restrict__ kbuf, const float* __restrict__ qlbuf,
    const float* __restrict__ Fbuf,
    float* __restrict__ out)
{
    __shared__ float sF[CH][20];  // [c]: 0-7 gg*A[e], 8-15 gl*B[e], 16 gg*S

    const int tid  = threadIdx.x;
    const int lane = tid & 63;
    const int g    = __builtin_amdgcn_readfirstlane(tid >> 6);  // 0..7
    const int b    = blockIdx.x >> 6;
    const int p    = ((blockIdx.x & 63) << 6) | lane;

    const float* Fb = Fbuf + b * PJ;

    // ---- coalesced F load -> LDS (already scaled by kr) ----
    {
        const int c = tid & 63, e = tid >> 6;
        sF[c][e]     = Fb[tid];                      // A
        sF[c][8 + e] = Fb[512 + tid];                // B
        if (tid < 64) sF[tid][16] = Fb[1024 + tid];  // S
    }

    // ---- prefetch streams (independent of LDS) ----
    const float* kgp = kbuf + ((size_t)b << 15) + ((size_t)p << 3);
    const float4 kg0 = *reinterpret_cast<const float4*>(kgp);
    const float4 kg1 = *reinterpret_cast<const float4*>(kgp + 4);
    float ql[CE];
#pragma unroll
    for (int e = 0; e < CE; ++e) ql[e] = qlbuf[(((b << 3) + e) << 12) + p];
    const int c0 = g << 3;        // scalar: this wave's 8 channels
    float xr[8];
#pragma unroll
    for (int ci = 0; ci < 8; ++ci) xr[ci] = x[(((b << 6) + c0 + ci) << 12) + p];

    __syncthreads();

    // ---- phase B: 8 channels per wave; wave-uniform b128 LDS broadcasts ----
#pragma unroll
    for (int ci = 0; ci < 8; ++ci) {
        const int c = c0 + ci;    // scalar
        const float4 A0 = *reinterpret_cast<const float4*>(&sF[c][0]);
        const float4 A1 = *reinterpret_cast<const float4*>(&sF[c][4]);
        const float4 B0 = *reinterpret_cast<const float4*>(&sF[c][8]);
        const float4 B1 = *reinterpret_cast<const float4*>(&sF[c][12]);
        float r = sF[c][16];
        r += kg0.x * A0.x + kg0.y * A0.y + kg0.z * A0.z + kg0.w * A0.w;
        r += kg1.x * A1.x + kg1.y * A1.y + kg1.z * A1.z + kg1.w * A1.w;
        r += ql[0] * B0.x + ql[1] * B0.y + ql[2] * B0.z + ql[3] * B0.w;
        r += ql[4] * B1.x + ql[5] * B1.y + ql[6] * B1.z + ql[7] * B1.w;
        const int idx = (((b << 6) + c) << 12) + p;
        out[idx] = r + xr[ci];
    }
}

extern "C" void kernel_launch(void* const* d_in, const int* in_sizes, int n_in,
                              void* d_out, int out_size, void* d_ws, size_t ws_size,
                              hipStream_t stream) {
    const float* x   = (const float*)d_in[0];
    const float* qlw = (const float*)d_in[1];
    const float* qlb = (const float*)d_in[2];
    const float* kw  = (const float*)d_in[3];
    const float* kb  = (const float*)d_in[4];
    const float* vw  = (const float*)d_in[5];
    const float* vb  = (const float*)d_in[6];
    const float* qgw = (const float*)d_in[7];
    const float* qgb = (const float*)d_in[8];
    const float* gg  = (const float*)d_in[9];
    const float* gl  = (const float*)d_in[10];
    float* out = (float*)d_out;

    float* ws    = (float*)d_ws;
    float* kbuf  = ws;                        // 4*8*4096 = 131072 f
    float* qlbuf = kbuf + BSZ * CE * HW;      // 131072 f
    float* Pbuf  = qlbuf + BSZ * CE * HW;     // 256*1088 = 278528 f
    float* Fbuf  = Pbuf + 256 * PJ;           // 4*1088   = 4352 f

    k1_kernel<<<256, 512, 0, stream>>>(x, qlw, qlb, kw, kb, vw, vb, qgw, qgb,
                                       kbuf, qlbuf, Pbuf);
    kr_kernel<<<68, 256, 0, stream>>>(Pbuf, gg, gl, Fbuf);
    k2_kernel<<<256, 512, 0, stream>>>(x, kbuf, qlbuf, Fbuf, out);
}

// Round 18
// 23.178 us; speedup vs baseline: 1.2521x; 1.2521x over previous
//
#include <hip/hip_runtime.h>

#define BSZ 4
#define CH  64
#define CE  8      // C/8
#define HW  4096
#define PJ  1088   // per-block partials: A 512 + B 512 + S 64

// ---------------------------------------------------------------------------
// K1: EXACT R15/R13 k1 (2.2 us measured; VGPR ~44, no spill, cold==warm).
// Per block = (batch b, 64 columns). Conv weights via scalar pipe; per-o
// remat of x is L1-hit and harmless (fix attempts: R14 c-chunk -> spill 5x;
// R16 16-wave -> L1 thrash; R17 volatile-asm pin -> serialized loads 18x).
// k/q_l -> global; v -> LDS; block-partial A/B/S -> own Pbuf slot.
// ---------------------------------------------------------------------------
__global__ __launch_bounds__(512) void k1_kernel(
    const float* __restrict__ x,
    const float* __restrict__ qlw, const float* __restrict__ qlb,
    const float* __restrict__ kw,  const float* __restrict__ kb,
    const float* __restrict__ vw,  const float* __restrict__ vb,
    const float* __restrict__ qgw, const float* __restrict__ qgb,
    float* __restrict__ kbuf, float* __restrict__ qlbuf, float* __restrict__ Pbuf)
{
    __shared__ float vT[CH][68];     // [channel][pp]
    __shared__ float kT[CE][64];     // [e][pp]

    const int tid  = threadIdx.x;
    const int lane = tid & 63;
    const int g    = __builtin_amdgcn_readfirstlane(tid >> 6);  // wave 0..7
    const int b    = blockIdx.x >> 6;
    const int p0   = (blockIdx.x & 63) << 6;
    const int p    = p0 | lane;

    float xv[CH];
#pragma unroll
    for (int c = 0; c < CH; ++c) xv[c] = x[(((b << 6) + c) << 12) + p];

    const int o0 = g * 10;           // scalar
#pragma unroll
    for (int i = 0; i < 10; ++i) {
        const int o = o0 + i;        // scalar 0..79
        const float* wr;
        float bias;
        if (o < 8)       { wr = kw  + (o << 6);        bias = kb[o]; }
        else if (o < 16) { wr = qlw + ((o - 8) << 6);  bias = qlb[o - 8]; }
        else             { wr = vw  + ((o - 16) << 6); bias = vb[o - 16]; }
        float acc = bias;
#pragma unroll
        for (int c = 0; c < CH; ++c) acc += wr[c] * xv[c];   // v_fmac v,s,v
        if (o < 8) {
            kbuf[(((b << 3) + o) << 12) + p] = acc;
            kT[o][lane] = acc;
        } else if (o < 16) {
            qlbuf[(((b << 3) + (o - 8)) << 12) + p] = acc;
        } else {
            vT[o - 16][lane] = acc;
        }
    }
    __syncthreads();

    {
        const int e = g & 7;         // scalar
        float a = 0.f, bb = 0.f;
#pragma unroll
        for (int pp = 0; pp < 64; pp += 4) {
            const float4 vv = *reinterpret_cast<const float4*>(&vT[lane][pp]);
            const float4 kk = *reinterpret_cast<const float4*>(&kT[e][pp]);
            const float w0 = qgw[((p0 + pp + 0) << 3) + e];   // s_load
            const float w1 = qgw[((p0 + pp + 1) << 3) + e];
            const float w2 = qgw[((p0 + pp + 2) << 3) + e];
            const float w3 = qgw[((p0 + pp + 3) << 3) + e];
            a  += vv.x * w0 + vv.y * w1 + vv.z * w2 + vv.w * w3;
            bb += vv.x * kk.x + vv.y * kk.y + vv.z * kk.z + vv.w * kk.w;
        }
        float* P = Pbuf + (size_t)blockIdx.x * PJ;
        P[(e << 6) + lane] = a;              // coalesced per wave
        P[512 + (e << 6) + lane] = bb;
        if (g == 0) {
            float s = 0.f;
#pragma unroll
            for (int pp = 0; pp < 64; pp += 4) {
                const float4 vv = *reinterpret_cast<const float4*>(&vT[lane][pp]);
                s += vv.x * qgb[p0 + pp] + vv.y * qgb[p0 + pp + 1]
                   + vv.z * qgb[p0 + pp + 2] + vv.w * qgb[p0 + pp + 3];
            }
            P[1024 + lane] = s;
        }
    }
}

// ---------------------------------------------------------------------------
// KR: EXACT R15. 68 blocks x 256 threads; block owns 64 consecutive j;
// wave-loads are 64 consecutive floats (full cache lines); 16 independent
// loads/thread; LDS [4][64] combine; gg/gl folded HERE (and only here).
// ---------------------------------------------------------------------------
__global__ __launch_bounds__(256) void kr_kernel(
    const float* __restrict__ Pbuf,
    const float* __restrict__ ggp, const float* __restrict__ glp,
    float* __restrict__ Fbuf)
{
    __shared__ float red[4][64];

    const int t    = threadIdx.x;
    const int jl   = t & 63;
    const int grp  = t >> 6;                         // 0..3
    const int j0   = blockIdx.x << 6;                // 0,64,...,4288
    const int b    = __builtin_amdgcn_readfirstlane(j0 / PJ);
    const int jj   = (j0 - b * PJ) + jl;             // 0..1087

    const float* Pb = Pbuf + ((size_t)(b << 6) + (grp << 4)) * PJ + jj;
    float acc = 0.f;
#pragma unroll
    for (int s = 0; s < 16; ++s) acc += Pb[(size_t)s * PJ];  // coalesced

    red[grp][jl] = acc;
    __syncthreads();

    if (t < 64) {
        const float sum = red[0][t] + red[1][t] + red[2][t] + red[3][t];
        const int jjo = (j0 - b * PJ) + t;
        const float scale = (jjo >= 512 && jjo < 1024) ? glp[0] : ggp[0];
        Fbuf[j0 + t] = scale * sum;                  // coalesced
    }
}

// ---------------------------------------------------------------------------
// K2: EXACT R15. F staged through LDS via coalesced VMEM loads (raw; gg/gl
// already folded by kr). kg/ql/x register-prefetched before the barrier.
//   out[b,c,p] = dot8(kg[p],ggA[c]) + ggS[c] + dot8(ql[p],glB[c]) + x[b,c,p]
// kg[b,p,e] = kbuf flat at b*32768 + p*8 + e (raw reshape regroup).
// ---------------------------------------------------------------------------
__global__ __launch_bounds__(512) void k2_kernel(
    const float* __restrict__ x,
    const float* __restrict__ kbuf, const float* __restrict__ qlbuf,
    const float* __restrict__ Fbuf,
    float* __restrict__ out)
{
    __shared__ float sF[CH][20];  // [c]: 0-7 gg*A[e], 8-15 gl*B[e], 16 gg*S

    const int tid  = threadIdx.x;
    const int lane = tid & 63;
    const int g    = __builtin_amdgcn_readfirstlane(tid >> 6);  // 0..7
    const int b    = blockIdx.x >> 6;
    const int p    = ((blockIdx.x & 63) << 6) | lane;

    const float* Fb = Fbuf + b * PJ;

    // ---- coalesced F load -> LDS (already scaled by kr) ----
    {
        const int c = tid & 63, e = tid >> 6;
        sF[c][e]     = Fb[tid];                      // A
        sF[c][8 + e] = Fb[512 + tid];                // B
        if (tid < 64) sF[tid][16] = Fb[1024 + tid];  // S
    }

    // ---- prefetch streams (independent of LDS) ----
    const float* kgp = kbuf + ((size_t)b << 15) + ((size_t)p << 3);
    const float4 kg0 = *reinterpret_cast<const float4*>(kgp);
    const float4 kg1 = *reinterpret_cast<const float4*>(kgp + 4);
    float ql[CE];
#pragma unroll
    for (int e = 0; e < CE; ++e) ql[e] = qlbuf[(((b << 3) + e) << 12) + p];
    const int c0 = g << 3;        // scalar: this wave's 8 channels
    float xr[8];
#pragma unroll
    for (int ci = 0; ci < 8; ++ci) xr[ci] = x[(((b << 6) + c0 + ci) << 12) + p];

    __syncthreads();

    // ---- phase B: 8 channels per wave; wave-uniform b128 LDS broadcasts ----
#pragma unroll
    for (int ci = 0; ci < 8; ++ci) {
        const int c = c0 + ci;    // scalar
        const float4 A0 = *reinterpret_cast<const float4*>(&sF[c][0]);
        const float4 A1 = *reinterpret_cast<const float4*>(&sF[c][4]);
        const float4 B0 = *reinterpret_cast<const float4*>(&sF[c][8]);
        const float4 B1 = *reinterpret_cast<const float4*>(&sF[c][12]);
        float r = sF[c][16];
        r += kg0.x * A0.x + kg0.y * A0.y + kg0.z * A0.z + kg0.w * A0.w;
        r += kg1.x * A1.x + kg1.y * A1.y + kg1.z * A1.z + kg1.w * A1.w;
        r += ql[0] * B0.x + ql[1] * B0.y + ql[2] * B0.z + ql[3] * B0.w;
        r += ql[4] * B1.x + ql[5] * B1.y + ql[6] * B1.z + ql[7] * B1.w;
        const int idx = (((b << 6) + c) << 12) + p;
        out[idx] = r + xr[ci];
    }
}

extern "C" void kernel_launch(void* const* d_in, const int* in_sizes, int n_in,
                              void* d_out, int out_size, void* d_ws, size_t ws_size,
                              hipStream_t stream) {
    const float* x   = (const float*)d_in[0];
    const float* qlw = (const float*)d_in[1];
    const float* qlb = (const float*)d_in[2];
    const float* kw  = (const float*)d_in[3];
    const float* kb  = (const float*)d_in[4];
    const float* vw  = (const float*)d_in[5];
    const float* vb  = (const float*)d_in[6];
    const float* qgw = (const float*)d_in[7];
    const float* qgb = (const float*)d_in[8];
    const float* gg  = (const float*)d_in[9];
    const float* gl  = (const float*)d_in[10];
    float* out = (float*)d_out;

    float* ws    = (float*)d_ws;
    float* kbuf  = ws;                        // 4*8*4096 = 131072 f
    float* qlbuf = kbuf + BSZ * CE * HW;      // 131072 f
    float* Pbuf  = qlbuf + BSZ * CE * HW;     // 256*1088 = 278528 f
    float* Fbuf  = Pbuf + 256 * PJ;           // 4*1088   = 4352 f

    k1_kernel<<<256, 512, 0, stream>>>(x, qlw, qlb, kw, kb, vw, vb, qgw, qgb,
                                       kbuf, qlbuf, Pbuf);
    kr_kernel<<<68, 256, 0, stream>>>(Pbuf, gg, gl, Fbuf);
    k2_kernel<<<256, 512, 0, stream>>>(x, kbuf, qlbuf, Fbuf, out);
}